// Round 1
// baseline (961.075 us; speedup 1.0000x reference)
//
#include <hip/hip_runtime.h>

#define NNODES 50000
#define NEDGES 800000
#define HD 128
#define NG 512
#define BN_EPS 1e-5f

// ---------------- CSR build ----------------

__global__ void hist_kernel(const int* __restrict__ dst, int* __restrict__ cnt, int n) {
    int i = blockIdx.x * 256 + threadIdx.x;
    if (i < n) atomicAdd(&cnt[dst[i]], 1);
}

__global__ void scan1_kernel(const int* __restrict__ cnt, int* __restrict__ incl,
                             int* __restrict__ bsum, int n) {
    __shared__ int s[1024];
    int i = blockIdx.x * 1024 + threadIdx.x;
    int v = (i < n) ? cnt[i] : 0;
    s[threadIdx.x] = v;
    __syncthreads();
    for (int off = 1; off < 1024; off <<= 1) {
        int add = (threadIdx.x >= off) ? s[threadIdx.x - off] : 0;
        __syncthreads();
        s[threadIdx.x] += add;
        __syncthreads();
    }
    if (i < n) incl[i] = s[threadIdx.x];
    if (threadIdx.x == 1023) bsum[blockIdx.x] = s[1023];
}

__global__ void scan2_kernel(const int* __restrict__ bsum, int* __restrict__ boffs, int nb) {
    __shared__ int s[64];
    int v = (threadIdx.x < nb) ? bsum[threadIdx.x] : 0;
    s[threadIdx.x] = v;
    __syncthreads();
    for (int off = 1; off < 64; off <<= 1) {
        int add = (threadIdx.x >= off) ? s[threadIdx.x - off] : 0;
        __syncthreads();
        s[threadIdx.x] += add;
        __syncthreads();
    }
    if (threadIdx.x < nb) boffs[threadIdx.x] = s[threadIdx.x] - v;  // exclusive
}

__global__ void scan3_kernel(const int* __restrict__ incl, const int* __restrict__ boffs,
                             int* __restrict__ rowp, int n) {
    int i = blockIdx.x * 256 + threadIdx.x;
    if (i < n) rowp[i + 1] = incl[i] + boffs[i >> 10];
    if (i == 0) rowp[0] = 0;
}

__global__ void build_kernel(const int* __restrict__ src, const int* __restrict__ dst,
                             const int* __restrict__ rowp, int* __restrict__ fill,
                             int* __restrict__ colv, int n) {
    int i = blockIdx.x * 256 + threadIdx.x;
    if (i < n) {
        int d = dst[i];
        int pos = rowp[d] + atomicAdd(&fill[d], 1);
        colv[pos] = src[i];
    }
}

// ---------------- aggregation: tmp[i] = h[i] + sum_{j in in(i)} h[src_j] ----------------

__global__ __launch_bounds__(256) void aggregate_kernel(
    const float* __restrict__ h, const int* __restrict__ rowp,
    const int* __restrict__ colv, float* __restrict__ outv, int n) {
    int node = blockIdx.x * 8 + (threadIdx.x >> 5);
    int lane = threadIdx.x & 31;
    if (node >= n) return;
    int beg = rowp[node], end = rowp[node + 1];
    const float4* hp = (const float4*)h;
    float4 a = hp[(size_t)node * 32 + lane];
    for (int j = beg; j < end; ++j) {
        int s = colv[j];
        float4 v = hp[(size_t)s * 32 + lane];
        a.x += v.x; a.y += v.y; a.z += v.z; a.w += v.w;
    }
    ((float4*)outv)[(size_t)node * 32 + lane] = a;
}

// ---------------- GEMM [N,128] @ [128,128] + bias, optional fused BN/relu/stats --------

template <bool PRE_BN, bool STATS, bool POST_RELU>
__global__ __launch_bounds__(256) void gemm128_kernel(
    const float* __restrict__ in, const float* __restrict__ W,
    const float* __restrict__ bias, float* __restrict__ out,
    const float* __restrict__ scale, const float* __restrict__ shift,
    float* __restrict__ ssum, float* __restrict__ ssq, int nrows) {
    __shared__ float lds[32 * 128];
    const int t = threadIdx.x;
    const int row0 = blockIdx.x * 32;

    // stage 32x128 input tile (apply BN+relu elementwise if PRE_BN)
    {
        const float4* inp4 = (const float4*)(in + (size_t)row0 * HD);
        float4* l4 = (float4*)lds;
#pragma unroll
        for (int i = 0; i < 4; ++i) {
            int f4 = t + i * 256;
            int r = f4 >> 5;
            float4 v = make_float4(0.f, 0.f, 0.f, 0.f);
            if (row0 + r < nrows) v = inp4[f4];
            if (PRE_BN) {
                int c4 = f4 & 31;
                float4 sc = ((const float4*)scale)[c4];
                float4 sh = ((const float4*)shift)[c4];
                v.x = fmaxf(fmaf(v.x, sc.x, sh.x), 0.f);
                v.y = fmaxf(fmaf(v.y, sc.y, sh.y), 0.f);
                v.z = fmaxf(fmaf(v.z, sc.z, sh.z), 0.f);
                v.w = fmaxf(fmaf(v.w, sc.w, sh.w), 0.f);
            }
            l4[f4] = v;
        }
    }
    __syncthreads();

    const int col = t & 127;
    const int rh = t >> 7;  // 0 or 1: rows rh*16 .. rh*16+15
    float b = bias[col];
    float acc[16];
#pragma unroll
    for (int r = 0; r < 16; ++r) acc[r] = b;

#pragma unroll 1
    for (int kc = 0; kc < 4; ++kc) {
        float w[32];
#pragma unroll
        for (int j = 0; j < 32; ++j) w[j] = W[(kc * 32 + j) * HD + col];
#pragma unroll
        for (int r = 0; r < 16; ++r) {
            const float4* rp = (const float4*)&lds[(rh * 16 + r) * HD + kc * 32];
#pragma unroll
            for (int j = 0; j < 8; ++j) {
                float4 v = rp[j];
                acc[r] = fmaf(v.x, w[4 * j + 0], acc[r]);
                acc[r] = fmaf(v.y, w[4 * j + 1], acc[r]);
                acc[r] = fmaf(v.z, w[4 * j + 2], acc[r]);
                acc[r] = fmaf(v.w, w[4 * j + 3], acc[r]);
            }
        }
    }

#pragma unroll
    for (int r = 0; r < 16; ++r) {
        int grow = row0 + rh * 16 + r;
        if (grow < nrows) {
            float v = acc[r];
            if (POST_RELU) v = fmaxf(v, 0.f);
            out[(size_t)grow * HD + col] = v;
        }
    }

    if (STATS) {
        float ls = 0.f, lq = 0.f;
#pragma unroll
        for (int r = 0; r < 16; ++r) {
            int grow = row0 + rh * 16 + r;
            if (grow < nrows) { ls += acc[r]; lq += acc[r] * acc[r]; }
        }
        __syncthreads();
        lds[t] = ls;
        lds[256 + t] = lq;
        __syncthreads();
        if (rh == 0) {
            atomicAdd(&ssum[col], lds[col] + lds[col + 128]);
            atomicAdd(&ssq[col], lds[256 + col] + lds[256 + col + 128]);
        }
    }
}

__global__ void finalize_stats_kernel(const float* __restrict__ s, const float* __restrict__ q,
                                      const float* __restrict__ gamma, const float* __restrict__ beta,
                                      float* __restrict__ scale, float* __restrict__ shift, int n) {
    int c = threadIdx.x;
    float mean = s[c] / (float)n;
    float var = q[c] / (float)n - mean * mean;
    float rstd = rsqrtf(var + BN_EPS);
    float sc = gamma[c] * rstd;
    scale[c] = sc;
    shift[c] = beta[c] - mean * sc;
}

// ---------------- readout: segment-sum over ptr ranges ----------------

__global__ void readout_kernel(const float* __restrict__ h, const int* __restrict__ ptr,
                               float* __restrict__ out) {
    int g = blockIdx.x;
    int lane = threadIdx.x;  // 128
    int beg = ptr[g], end = ptr[g + 1];
    float a = 0.f;
    for (int n = beg; n < end; ++n) a += h[(size_t)n * HD + lane];
    out[g * HD + lane] = a;
}

// ---------------- launch ----------------

extern "C" void kernel_launch(void* const* d_in, const int* in_sizes, int n_in,
                              void* d_out, int out_size, void* d_ws, size_t ws_size,
                              hipStream_t stream) {
    const float* x = (const float*)d_in[0];
    const int* esrc = (const int*)d_in[1];
    const int* edst = (const int*)d_in[2];
    const int* gptr = (const int*)d_in[3];
    const float* wA[3] = {(const float*)d_in[4], (const float*)d_in[10], (const float*)d_in[16]};
    const float* bA[3] = {(const float*)d_in[5], (const float*)d_in[11], (const float*)d_in[17]};
    const float* gm[3] = {(const float*)d_in[6], (const float*)d_in[12], (const float*)d_in[18]};
    const float* bt[3] = {(const float*)d_in[7], (const float*)d_in[13], (const float*)d_in[19]};
    const float* wB[3] = {(const float*)d_in[8], (const float*)d_in[14], (const float*)d_in[20]};
    const float* bB[3] = {(const float*)d_in[9], (const float*)d_in[15], (const float*)d_in[21]};

    char* w = (char*)d_ws;
    float* tmp = (float*)w; w += (size_t)NNODES * HD * 4;   // 25.6 MB
    float* zb  = (float*)w; w += (size_t)NNODES * HD * 4;   // 25.6 MB
    float* hb  = (float*)w; w += (size_t)NNODES * HD * 4;   // 25.6 MB
    int* colv  = (int*)w;   w += (size_t)NEDGES * 4;        // 3.2 MB
    int* incl  = (int*)w;   w += (size_t)NNODES * 4;
    int* rowp  = (int*)w;   w += ((size_t)(NNODES + 1) * 4 + 15) & ~(size_t)15;
    int* bsum  = (int*)w;   w += 64 * 4;
    int* boffs = (int*)w;   w += 64 * 4;
    // ---- zero region starts here (16B aligned) ----
    char* zero_base = w;
    int* cnt   = (int*)w;   w += (size_t)NNODES * 4;
    int* fill  = (int*)w;   w += (size_t)NNODES * 4;
    float* ssum   = (float*)w; w += 3 * 128 * 4;
    float* ssq    = (float*)w; w += 3 * 128 * 4;
    float* scaleb = (float*)w; w += 128 * 4;
    float* shiftb = (float*)w; w += 128 * 4;
    size_t zero_bytes = (size_t)(w - zero_base);

    hipMemsetAsync(zero_base, 0, zero_bytes, stream);

    // CSR by destination
    hist_kernel<<<(NEDGES + 255) / 256, 256, 0, stream>>>(edst, cnt, NEDGES);
    int nsb = (NNODES + 1023) / 1024;  // 49
    scan1_kernel<<<nsb, 1024, 0, stream>>>(cnt, incl, bsum, NNODES);
    scan2_kernel<<<1, 64, 0, stream>>>(bsum, boffs, nsb);
    scan3_kernel<<<(NNODES + 255) / 256, 256, 0, stream>>>(incl, boffs, rowp, NNODES);
    build_kernel<<<(NEDGES + 255) / 256, 256, 0, stream>>>(esrc, edst, rowp, fill, colv, NEDGES);

    const int gemm_grid = (NNODES + 31) / 32;  // 1563
    const float* hin = x;
    for (int l = 0; l < 3; ++l) {
        aggregate_kernel<<<(NNODES + 7) / 8, 256, 0, stream>>>(hin, rowp, colv, tmp, NNODES);
        gemm128_kernel<false, true, false><<<gemm_grid, 256, 0, stream>>>(
            tmp, wA[l], bA[l], zb, nullptr, nullptr, ssum + l * 128, ssq + l * 128, NNODES);
        finalize_stats_kernel<<<1, 128, 0, stream>>>(ssum + l * 128, ssq + l * 128,
                                                     gm[l], bt[l], scaleb, shiftb, NNODES);
        gemm128_kernel<true, false, true><<<gemm_grid, 256, 0, stream>>>(
            zb, wB[l], bB[l], hb, scaleb, shiftb, nullptr, nullptr, NNODES);
        hin = hb;
    }

    readout_kernel<<<NG, 128, 0, stream>>>(hb, gptr, (float*)d_out);
}

// Round 2
// 806.135 us; speedup vs baseline: 1.1922x; 1.1922x over previous
//
#include <hip/hip_runtime.h>

#define NNODES 50000
#define NEDGES 800000
#define HD 128
#define NG 512
#define BN_EPS 1e-5f

// ---------------- CSR build ----------------

__global__ void hist_kernel(const int* __restrict__ dst, int* __restrict__ cnt, int n) {
    int i = blockIdx.x * 256 + threadIdx.x;
    if (i < n) atomicAdd(&cnt[dst[i]], 1);
}

__global__ void scan1_kernel(const int* __restrict__ cnt, int* __restrict__ incl,
                             int* __restrict__ bsum, int n) {
    __shared__ int s[1024];
    int i = blockIdx.x * 1024 + threadIdx.x;
    int v = (i < n) ? cnt[i] : 0;
    s[threadIdx.x] = v;
    __syncthreads();
    for (int off = 1; off < 1024; off <<= 1) {
        int add = (threadIdx.x >= off) ? s[threadIdx.x - off] : 0;
        __syncthreads();
        s[threadIdx.x] += add;
        __syncthreads();
    }
    if (i < n) incl[i] = s[threadIdx.x];
    if (threadIdx.x == 1023) bsum[blockIdx.x] = s[1023];
}

__global__ void scan2_kernel(const int* __restrict__ bsum, int* __restrict__ boffs, int nb) {
    __shared__ int s[64];
    int v = (threadIdx.x < nb) ? bsum[threadIdx.x] : 0;
    s[threadIdx.x] = v;
    __syncthreads();
    for (int off = 1; off < 64; off <<= 1) {
        int add = (threadIdx.x >= off) ? s[threadIdx.x - off] : 0;
        __syncthreads();
        s[threadIdx.x] += add;
        __syncthreads();
    }
    if (threadIdx.x < nb) boffs[threadIdx.x] = s[threadIdx.x] - v;  // exclusive
}

__global__ void scan3_kernel(const int* __restrict__ incl, const int* __restrict__ boffs,
                             int* __restrict__ rowp, int n) {
    int i = blockIdx.x * 256 + threadIdx.x;
    if (i < n) rowp[i + 1] = incl[i] + boffs[i >> 10];
    if (i == 0) rowp[0] = 0;
}

__global__ void build_kernel(const int* __restrict__ src, const int* __restrict__ dst,
                             const int* __restrict__ rowp, int* __restrict__ fill,
                             int* __restrict__ colv, int n) {
    int i = blockIdx.x * 256 + threadIdx.x;
    if (i < n) {
        int d = dst[i];
        int pos = rowp[d] + atomicAdd(&fill[d], 1);
        colv[pos] = src[i];
    }
}

// ---------------- aggregation: tmp[i] = h[i] + sum_{j in in(i)} h[src_j] ----------------

__global__ __launch_bounds__(256) void aggregate_kernel(
    const float* __restrict__ h, const int* __restrict__ rowp,
    const int* __restrict__ colv, float* __restrict__ outv, int n) {
    int node = blockIdx.x * 8 + (threadIdx.x >> 5);
    int lane = threadIdx.x & 31;
    if (node >= n) return;
    int beg = rowp[node], end = rowp[node + 1];
    const float4* hp = (const float4*)h;
    float4 a = hp[(size_t)node * 32 + lane];
    for (int j = beg; j < end; ++j) {
        int s = colv[j];
        float4 v = hp[(size_t)s * 32 + lane];
        a.x += v.x; a.y += v.y; a.z += v.z; a.w += v.w;
    }
    ((float4*)outv)[(size_t)node * 32 + lane] = a;
}

// ---------------- GEMM [N,128] @ [128,128] + bias, fused BN/relu/stats/readout --------

template <bool PRE_BN, bool STATS, bool POST_RELU, bool FUSE_READOUT>
__global__ __launch_bounds__(256) void gemm128_kernel(
    const float* __restrict__ in, const float* __restrict__ W,
    const float* __restrict__ bias, float* __restrict__ out,
    const float* __restrict__ scale, const float* __restrict__ shift,
    float* __restrict__ ssum, float* __restrict__ ssq,
    const int* __restrict__ gptr, float* __restrict__ gout, int nrows) {
    __shared__ float lds[32 * 128];
    const int t = threadIdx.x;
    const int row0 = blockIdx.x * 32;

    // stage 32x128 input tile (apply BN+relu elementwise if PRE_BN)
    {
        const float4* inp4 = (const float4*)(in + (size_t)row0 * HD);
        float4* l4 = (float4*)lds;
#pragma unroll
        for (int i = 0; i < 4; ++i) {
            int f4 = t + i * 256;
            int r = f4 >> 5;
            float4 v = make_float4(0.f, 0.f, 0.f, 0.f);
            if (row0 + r < nrows) v = inp4[f4];
            if (PRE_BN) {
                int c4 = f4 & 31;
                float4 sc = ((const float4*)scale)[c4];
                float4 sh = ((const float4*)shift)[c4];
                v.x = fmaxf(fmaf(v.x, sc.x, sh.x), 0.f);
                v.y = fmaxf(fmaf(v.y, sc.y, sh.y), 0.f);
                v.z = fmaxf(fmaf(v.z, sc.z, sh.z), 0.f);
                v.w = fmaxf(fmaf(v.w, sc.w, sh.w), 0.f);
            }
            l4[f4] = v;
        }
    }
    __syncthreads();

    const int col = t & 127;
    const int rh = t >> 7;  // 0 or 1: rows rh*16 .. rh*16+15
    float b = bias[col];
    float acc[16];
#pragma unroll
    for (int r = 0; r < 16; ++r) acc[r] = b;

#pragma unroll 1
    for (int kc = 0; kc < 4; ++kc) {
        float w[32];
#pragma unroll
        for (int j = 0; j < 32; ++j) w[j] = W[(kc * 32 + j) * HD + col];
#pragma unroll
        for (int r = 0; r < 16; ++r) {
            const float4* rp = (const float4*)&lds[(rh * 16 + r) * HD + kc * 32];
#pragma unroll
            for (int j = 0; j < 8; ++j) {
                float4 v = rp[j];
                acc[r] = fmaf(v.x, w[4 * j + 0], acc[r]);
                acc[r] = fmaf(v.y, w[4 * j + 1], acc[r]);
                acc[r] = fmaf(v.z, w[4 * j + 2], acc[r]);
                acc[r] = fmaf(v.w, w[4 * j + 3], acc[r]);
            }
        }
    }

    if (!FUSE_READOUT) {
#pragma unroll
        for (int r = 0; r < 16; ++r) {
            int grow = row0 + rh * 16 + r;
            if (grow < nrows) {
                float v = acc[r];
                if (POST_RELU) v = fmaxf(v, 0.f);
                out[(size_t)grow * HD + col] = v;
            }
        }
    } else {
        // segment-sum the relu'd outputs directly into gout[seg*HD + col].
        // rows are sorted by segment; find seg of first row (searchsorted-right
        // semantics: largest seg with gptr[seg] <= row < gptr[seg+1], taking the
        // last among duplicate gptr entries), then walk forward.
        int first = row0 + rh * 16;
        int lo = 0, hi = NG - 1;
        while (lo < hi) {
            int mid = (lo + hi) >> 1;
            if (first >= gptr[mid + 1]) lo = mid + 1; else hi = mid;
        }
        int seg = lo;
        int segend = gptr[seg + 1];
        float run = 0.f;
#pragma unroll
        for (int r = 0; r < 16; ++r) {
            int grow = first + r;
            if (grow < nrows) {
                while (grow >= segend) {
                    if (run != 0.f) atomicAdd(&gout[seg * HD + col], run);
                    run = 0.f;
                    ++seg;
                    segend = gptr[seg + 1];
                }
                run += fmaxf(acc[r], 0.f);
            }
        }
        if (run != 0.f) atomicAdd(&gout[seg * HD + col], run);
    }

    if (STATS) {
        float ls = 0.f, lq = 0.f;
#pragma unroll
        for (int r = 0; r < 16; ++r) {
            int grow = row0 + rh * 16 + r;
            if (grow < nrows) { ls += acc[r]; lq += acc[r] * acc[r]; }
        }
        __syncthreads();
        lds[t] = ls;
        lds[256 + t] = lq;
        __syncthreads();
        if (rh == 0) {
            atomicAdd(&ssum[col], lds[col] + lds[col + 128]);
            atomicAdd(&ssq[col], lds[256 + col] + lds[256 + col + 128]);
        }
    }
}

__global__ void finalize_stats_kernel(const float* __restrict__ s, const float* __restrict__ q,
                                      const float* __restrict__ gamma, const float* __restrict__ beta,
                                      float* __restrict__ scale, float* __restrict__ shift, int n) {
    int c = threadIdx.x;
    float mean = s[c] / (float)n;
    float var = q[c] / (float)n - mean * mean;
    float rstd = rsqrtf(var + BN_EPS);
    float sc = gamma[c] * rstd;
    scale[c] = sc;
    shift[c] = beta[c] - mean * sc;
}

// ---------------- launch ----------------

extern "C" void kernel_launch(void* const* d_in, const int* in_sizes, int n_in,
                              void* d_out, int out_size, void* d_ws, size_t ws_size,
                              hipStream_t stream) {
    const float* x = (const float*)d_in[0];
    const int* esrc = (const int*)d_in[1];
    const int* edst = (const int*)d_in[2];
    const int* gptr = (const int*)d_in[3];
    const float* wA[3] = {(const float*)d_in[4], (const float*)d_in[10], (const float*)d_in[16]};
    const float* bA[3] = {(const float*)d_in[5], (const float*)d_in[11], (const float*)d_in[17]};
    const float* gm[3] = {(const float*)d_in[6], (const float*)d_in[12], (const float*)d_in[18]};
    const float* bt[3] = {(const float*)d_in[7], (const float*)d_in[13], (const float*)d_in[19]};
    const float* wB[3] = {(const float*)d_in[8], (const float*)d_in[14], (const float*)d_in[20]};
    const float* bB[3] = {(const float*)d_in[9], (const float*)d_in[15], (const float*)d_in[21]};

    char* w = (char*)d_ws;
    float* tmp = (float*)w; w += (size_t)NNODES * HD * 4;   // 25.6 MB
    float* zb  = (float*)w; w += (size_t)NNODES * HD * 4;   // 25.6 MB
    float* hb  = (float*)w; w += (size_t)NNODES * HD * 4;   // 25.6 MB
    int* colv  = (int*)w;   w += (size_t)NEDGES * 4;        // 3.2 MB
    int* incl  = (int*)w;   w += (size_t)NNODES * 4;
    int* rowp  = (int*)w;   w += ((size_t)(NNODES + 1) * 4 + 15) & ~(size_t)15;
    int* bsum  = (int*)w;   w += 64 * 4;
    int* boffs = (int*)w;   w += 64 * 4;
    // ---- zero region starts here (16B aligned) ----
    char* zero_base = w;
    int* cnt   = (int*)w;   w += (size_t)NNODES * 4;
    int* fill  = (int*)w;   w += (size_t)NNODES * 4;
    float* ssum   = (float*)w; w += 3 * 128 * 4;
    float* ssq    = (float*)w; w += 3 * 128 * 4;
    float* scaleb = (float*)w; w += 128 * 4;
    float* shiftb = (float*)w; w += 128 * 4;
    size_t zero_bytes = (size_t)(w - zero_base);

    hipMemsetAsync(zero_base, 0, zero_bytes, stream);
    hipMemsetAsync(d_out, 0, (size_t)NG * HD * 4, stream);

    // CSR by destination
    hist_kernel<<<(NEDGES + 255) / 256, 256, 0, stream>>>(edst, cnt, NEDGES);
    int nsb = (NNODES + 1023) / 1024;  // 49
    scan1_kernel<<<nsb, 1024, 0, stream>>>(cnt, incl, bsum, NNODES);
    scan2_kernel<<<1, 64, 0, stream>>>(bsum, boffs, nsb);
    scan3_kernel<<<(NNODES + 255) / 256, 256, 0, stream>>>(incl, boffs, rowp, NNODES);
    build_kernel<<<(NEDGES + 255) / 256, 256, 0, stream>>>(esrc, edst, rowp, fill, colv, NEDGES);

    const int gemm_grid = (NNODES + 31) / 32;  // 1563
    const float* hin = x;
    for (int l = 0; l < 3; ++l) {
        aggregate_kernel<<<(NNODES + 7) / 8, 256, 0, stream>>>(hin, rowp, colv, tmp, NNODES);
        gemm128_kernel<false, true, false, false><<<gemm_grid, 256, 0, stream>>>(
            tmp, wA[l], bA[l], zb, nullptr, nullptr, ssum + l * 128, ssq + l * 128,
            nullptr, nullptr, NNODES);
        finalize_stats_kernel<<<1, 128, 0, stream>>>(ssum + l * 128, ssq + l * 128,
                                                     gm[l], bt[l], scaleb, shiftb, NNODES);
        if (l < 2) {
            gemm128_kernel<true, false, true, false><<<gemm_grid, 256, 0, stream>>>(
                zb, wB[l], bB[l], hb, scaleb, shiftb, nullptr, nullptr,
                nullptr, nullptr, NNODES);
        } else {
            gemm128_kernel<true, false, true, true><<<gemm_grid, 256, 0, stream>>>(
                zb, wB[l], bB[l], nullptr, scaleb, shiftb, nullptr, nullptr,
                gptr, (float*)d_out, NNODES);
        }
        hin = hb;
    }
}

// Round 3
// 520.526 us; speedup vs baseline: 1.8464x; 1.5487x over previous
//
#include <hip/hip_runtime.h>

#define NNODES 50000
#define NEDGES 800000
#define HD 128
#define NG 512
#define BN_EPS 1e-5f

typedef short bf16x8 __attribute__((ext_vector_type(8)));
typedef float floatx4 __attribute__((ext_vector_type(4)));

union U16 { uint4 u; bf16x8 h; };

__device__ __forceinline__ ushort f2bf(float f) {
    unsigned u = __float_as_uint(f);
    return (ushort)((u + 0x7fffu + ((u >> 16) & 1u)) >> 16);
}
__device__ __forceinline__ void unpack8(const uint4& u, float* f) {
    const unsigned* w = (const unsigned*)&u;
#pragma unroll
    for (int i = 0; i < 4; ++i) {
        f[2 * i]     = __uint_as_float(w[i] << 16);
        f[2 * i + 1] = __uint_as_float(w[i] & 0xffff0000u);
    }
}
__device__ __forceinline__ uint4 pack8(const float* f) {
    uint4 o;
    unsigned* w = (unsigned*)&o;
#pragma unroll
    for (int i = 0; i < 4; ++i)
        w[i] = (unsigned)f2bf(f[2 * i]) | ((unsigned)f2bf(f[2 * i + 1]) << 16);
    return o;
}

// ---------------- CSR build ----------------

__global__ void hist_kernel(const int* __restrict__ dst, int* __restrict__ cnt, int n) {
    int i = blockIdx.x * 256 + threadIdx.x;
    if (i < n) atomicAdd(&cnt[dst[i]], 1);
}

__global__ void scan1_kernel(const int* __restrict__ cnt, int* __restrict__ incl,
                             int* __restrict__ bsum, int n) {
    __shared__ int s[1024];
    int i = blockIdx.x * 1024 + threadIdx.x;
    int v = (i < n) ? cnt[i] : 0;
    s[threadIdx.x] = v;
    __syncthreads();
    for (int off = 1; off < 1024; off <<= 1) {
        int add = (threadIdx.x >= off) ? s[threadIdx.x - off] : 0;
        __syncthreads();
        s[threadIdx.x] += add;
        __syncthreads();
    }
    if (i < n) incl[i] = s[threadIdx.x];
    if (threadIdx.x == 1023) bsum[blockIdx.x] = s[1023];
}

__global__ void scan2_kernel(const int* __restrict__ bsum, int* __restrict__ boffs, int nb) {
    __shared__ int s[64];
    int v = (threadIdx.x < nb) ? bsum[threadIdx.x] : 0;
    s[threadIdx.x] = v;
    __syncthreads();
    for (int off = 1; off < 64; off <<= 1) {
        int add = (threadIdx.x >= off) ? s[threadIdx.x - off] : 0;
        __syncthreads();
        s[threadIdx.x] += add;
        __syncthreads();
    }
    if (threadIdx.x < nb) boffs[threadIdx.x] = s[threadIdx.x] - v;  // exclusive
}

__global__ void scan3_kernel(const int* __restrict__ incl, const int* __restrict__ boffs,
                             int* __restrict__ rowp, int n) {
    int i = blockIdx.x * 256 + threadIdx.x;
    if (i < n) rowp[i + 1] = incl[i] + boffs[i >> 10];
    if (i == 0) rowp[0] = 0;
}

__global__ void build_kernel(const int* __restrict__ src, const int* __restrict__ dst,
                             const int* __restrict__ rowp, int* __restrict__ fill,
                             int* __restrict__ colv, int n) {
    int i = blockIdx.x * 256 + threadIdx.x;
    if (i < n) {
        int d = dst[i];
        int pos = rowp[d] + atomicAdd(&fill[d], 1);
        colv[pos] = src[i];
    }
}

// ---------------- fp32 -> bf16 convert ----------------

__global__ void cvt_kernel(const float* __restrict__ x, ushort* __restrict__ xb, int n4) {
    int i = blockIdx.x * 256 + threadIdx.x;
    if (i < n4) {
        float4 v = ((const float4*)x)[i];
        ushort4 o;
        o.x = f2bf(v.x); o.y = f2bf(v.y); o.z = f2bf(v.z); o.w = f2bf(v.w);
        ((ushort4*)xb)[i] = o;
    }
}

// ---------------- pack weights into MFMA B-fragment order (bf16) ----------------
// B-frag for mfma_f32_16x16x32_bf16: lane reads B[k=quad*8+j][n=l16] for its (ct,kc).
// Wf flat index: ((ct*4+kc)*64 + lane)*8 + j

struct WP6 { const float* w[6]; };

__global__ void wfrag_kernel(WP6 p, ushort* __restrict__ wf) {
    const float* W = p.w[blockIdx.x];
    ushort* o = wf + (size_t)blockIdx.x * 16384;
    for (int i = threadIdx.x; i < 16384; i += 256) {
        int j = i & 7, lane = (i >> 3) & 63, kc = (i >> 9) & 3, ct = i >> 11;
        int k = kc * 32 + (lane >> 4) * 8 + j;
        int n = ct * 16 + (lane & 15);
        o[i] = f2bf(W[k * HD + n]);
    }
}

// ---------------- aggregation (bf16 rows, fp32 accumulate) ----------------

__global__ __launch_bounds__(256) void aggregate_kernel(
    const ushort* __restrict__ h, const int* __restrict__ rowp,
    const int* __restrict__ colv, ushort* __restrict__ outv, int n) {
    int node = blockIdx.x * 16 + (threadIdx.x >> 4);
    int l = threadIdx.x & 15;  // 16 lanes/node, 16B each
    if (node >= n) return;
    int beg = rowp[node], end = rowp[node + 1];
    const uint4* hp = (const uint4*)h;
    float a[8];
    uint4 sv = hp[(size_t)node * 16 + l];
    unpack8(sv, a);
    for (int j = beg; j < end; ++j) {
        uint4 v = hp[(size_t)colv[j] * 16 + l];
        float b[8];
        unpack8(v, b);
#pragma unroll
        for (int i = 0; i < 8; ++i) a[i] += b[i];
    }
    ((uint4*)outv)[(size_t)node * 16 + l] = pack8(a);
}

// ---------------- MFMA GEMM: [N,128](bf16) @ [128,128](bf16 frags) + bias ----------
// block = 64 rows, 4 waves x 16 rows; per wave: 8 col-tiles x 4 k-chunks of 16x16x32.
// A-frags straight from global (L2/LLC), B-frags from global (L1-hot, 32KB).

template <bool STATS, bool PRE_BN, bool READOUT>
__global__ __launch_bounds__(256) void mfma_gemm_kernel(
    const ushort* __restrict__ A, const ushort* __restrict__ Wf,
    const float* __restrict__ bias, ushort* __restrict__ out,
    const float* __restrict__ scale, const float* __restrict__ shift,
    float* __restrict__ ssum, float* __restrict__ ssq,
    const int* __restrict__ gptr, float* __restrict__ gout, int nrows) {
    __shared__ float reds[4][HD];
    __shared__ float redq[4][HD];
    const int t = threadIdx.x;
    const int wave = t >> 6, lane = t & 63;
    const int quad = lane >> 4, l16 = lane & 15;
    const int rowA = blockIdx.x * 64 + wave * 16 + l16;  // A-operand row for this lane

    floatx4 zf = {0.f, 0.f, 0.f, 0.f};
    floatx4 acc[8];
#pragma unroll
    for (int i = 0; i < 8; ++i) acc[i] = zf;

    const uint4* Wf4 = (const uint4*)Wf;

#pragma unroll
    for (int kc = 0; kc < 4; ++kc) {
        U16 au;
        if (rowA < nrows) {
            au.u = *(const uint4*)(A + (size_t)rowA * HD + kc * 32 + quad * 8);
            if (PRE_BN) {
                float f[8];
                unpack8(au.u, f);
                int kb = kc * 32 + quad * 8;
                float4 s0 = ((const float4*)(scale + kb))[0];
                float4 s1 = ((const float4*)(scale + kb))[1];
                float4 h0 = ((const float4*)(shift + kb))[0];
                float4 h1 = ((const float4*)(shift + kb))[1];
                f[0] = fmaxf(fmaf(f[0], s0.x, h0.x), 0.f);
                f[1] = fmaxf(fmaf(f[1], s0.y, h0.y), 0.f);
                f[2] = fmaxf(fmaf(f[2], s0.z, h0.z), 0.f);
                f[3] = fmaxf(fmaf(f[3], s0.w, h0.w), 0.f);
                f[4] = fmaxf(fmaf(f[4], s1.x, h1.x), 0.f);
                f[5] = fmaxf(fmaf(f[5], s1.y, h1.y), 0.f);
                f[6] = fmaxf(fmaf(f[6], s1.z, h1.z), 0.f);
                f[7] = fmaxf(fmaf(f[7], s1.w, h1.w), 0.f);
                au.u = pack8(f);
            }
        } else {
            au.u = make_uint4(0, 0, 0, 0);
        }
#pragma unroll
        for (int ct = 0; ct < 8; ++ct) {
            U16 bu;
            bu.u = Wf4[(ct * 4 + kc) * 64 + lane];
            acc[ct] = __builtin_amdgcn_mfma_f32_16x16x32_bf16(au.h, bu.h, acc[ct], 0, 0, 0);
        }
    }

    // C/D layout: col = ct*16 + l16, row = blockIdx*64 + wave*16 + quad*4 + reg
    const int r_base = blockIdx.x * 64 + wave * 16 + quad * 4;

    if (READOUT) {
        int segr[4] = {-1, -1, -1, -1};
        if (r_base < nrows) {
            int lo = 0, hi = NG - 1;
            while (lo < hi) {
                int mid = (lo + hi) >> 1;
                if (r_base >= gptr[mid + 1]) lo = mid + 1; else hi = mid;
            }
            int sg = lo;
#pragma unroll
            for (int reg = 0; reg < 4; ++reg) {
                int rw = r_base + reg;
                if (rw < nrows) {
                    while (rw >= gptr[sg + 1]) ++sg;
                    segr[reg] = sg;
                }
            }
        }
#pragma unroll
        for (int ct = 0; ct < 8; ++ct) {
            int col = ct * 16 + l16;
            float b = bias[col];
            float run = 0.f;
            int cur = segr[0];
#pragma unroll
            for (int reg = 0; reg < 4; ++reg) {
                if (segr[reg] != cur) {
                    if (cur >= 0 && run != 0.f) atomicAdd(&gout[cur * HD + col], run);
                    run = 0.f;
                    cur = segr[reg];
                }
                if (cur >= 0) run += fmaxf(acc[ct][reg] + b, 0.f);
            }
            if (cur >= 0 && run != 0.f) atomicAdd(&gout[cur * HD + col], run);
        }
    } else {
#pragma unroll
        for (int ct = 0; ct < 8; ++ct) {
            int col = ct * 16 + l16;
            float b = bias[col];
            float s = 0.f, q = 0.f;
#pragma unroll
            for (int reg = 0; reg < 4; ++reg) {
                int rw = r_base + reg;
                if (rw < nrows) {
                    float v = acc[ct][reg] + b;
                    if (!STATS) v = fmaxf(v, 0.f);  // GEMM-B: relu; GEMM-A: raw pre-BN
                    out[(size_t)rw * HD + col] = f2bf(v);
                    if (STATS) { s += v; q += v * v; }
                }
            }
            if (STATS) {
                s += __shfl_xor(s, 16); s += __shfl_xor(s, 32);
                q += __shfl_xor(q, 16); q += __shfl_xor(q, 32);
                if (quad == 0) { reds[wave][col] = s; redq[wave][col] = q; }
            }
        }
        if (STATS) {
            __syncthreads();
            if (t < HD) {
                atomicAdd(&ssum[t], reds[0][t] + reds[1][t] + reds[2][t] + reds[3][t]);
            } else {
                int c = t - HD;
                atomicAdd(&ssq[c], redq[0][c] + redq[1][c] + redq[2][c] + redq[3][c]);
            }
        }
    }
}

__global__ void finalize_stats_kernel(const float* __restrict__ s, const float* __restrict__ q,
                                      const float* __restrict__ gamma, const float* __restrict__ beta,
                                      float* __restrict__ scale, float* __restrict__ shift, int n) {
    int c = threadIdx.x;
    float mean = s[c] / (float)n;
    float var = q[c] / (float)n - mean * mean;
    float rstd = rsqrtf(var + BN_EPS);
    float sc = gamma[c] * rstd;
    scale[c] = sc;
    shift[c] = beta[c] - mean * sc;
}

// ---------------- launch ----------------

extern "C" void kernel_launch(void* const* d_in, const int* in_sizes, int n_in,
                              void* d_out, int out_size, void* d_ws, size_t ws_size,
                              hipStream_t stream) {
    const float* x = (const float*)d_in[0];
    const int* esrc = (const int*)d_in[1];
    const int* edst = (const int*)d_in[2];
    const int* gptr = (const int*)d_in[3];
    const float* wA[3] = {(const float*)d_in[4], (const float*)d_in[10], (const float*)d_in[16]};
    const float* bA[3] = {(const float*)d_in[5], (const float*)d_in[11], (const float*)d_in[17]};
    const float* gm[3] = {(const float*)d_in[6], (const float*)d_in[12], (const float*)d_in[18]};
    const float* bt[3] = {(const float*)d_in[7], (const float*)d_in[13], (const float*)d_in[19]};
    const float* wB[3] = {(const float*)d_in[8], (const float*)d_in[14], (const float*)d_in[20]};
    const float* bB[3] = {(const float*)d_in[9], (const float*)d_in[15], (const float*)d_in[21]};

    char* w = (char*)d_ws;
    ushort* xb   = (ushort*)w; w += (size_t)NNODES * HD * 2;  // 12.8 MB
    ushort* tmpb = (ushort*)w; w += (size_t)NNODES * HD * 2;
    ushort* zbb  = (ushort*)w; w += (size_t)NNODES * HD * 2;
    ushort* hbb  = (ushort*)w; w += (size_t)NNODES * HD * 2;
    ushort* wf   = (ushort*)w; w += (size_t)6 * 16384 * 2;    // 192 KB
    int* colv  = (int*)w;   w += (size_t)NEDGES * 4;
    int* incl  = (int*)w;   w += (size_t)NNODES * 4;
    int* rowp  = (int*)w;   w += ((size_t)(NNODES + 1) * 4 + 15) & ~(size_t)15;
    int* bsum  = (int*)w;   w += 64 * 4;
    int* boffs = (int*)w;   w += 64 * 4;
    // ---- zero region ----
    char* zero_base = w;
    int* cnt   = (int*)w;   w += (size_t)NNODES * 4;
    int* fill  = (int*)w;   w += (size_t)NNODES * 4;
    float* ssum   = (float*)w; w += 3 * 128 * 4;
    float* ssq    = (float*)w; w += 3 * 128 * 4;
    float* scaleb = (float*)w; w += 128 * 4;
    float* shiftb = (float*)w; w += 128 * 4;
    size_t zero_bytes = (size_t)(w - zero_base);

    hipMemsetAsync(zero_base, 0, zero_bytes, stream);
    hipMemsetAsync(d_out, 0, (size_t)NG * HD * 4, stream);

    // CSR by destination
    hist_kernel<<<(NEDGES + 255) / 256, 256, 0, stream>>>(edst, cnt, NEDGES);
    int nsb = (NNODES + 1023) / 1024;  // 49
    scan1_kernel<<<nsb, 1024, 0, stream>>>(cnt, incl, bsum, NNODES);
    scan2_kernel<<<1, 64, 0, stream>>>(bsum, boffs, nsb);
    scan3_kernel<<<(NNODES + 255) / 256, 256, 0, stream>>>(incl, boffs, rowp, NNODES);
    build_kernel<<<(NEDGES + 255) / 256, 256, 0, stream>>>(esrc, edst, rowp, fill, colv, NEDGES);

    // bf16 conversions
    cvt_kernel<<<(NNODES * HD / 4 + 255) / 256, 256, 0, stream>>>(x, xb, NNODES * HD / 4);
    WP6 wp;
    wp.w[0] = wA[0]; wp.w[1] = wB[0]; wp.w[2] = wA[1];
    wp.w[3] = wB[1]; wp.w[4] = wA[2]; wp.w[5] = wB[2];
    wfrag_kernel<<<6, 256, 0, stream>>>(wp, wf);

    const int gemm_grid = (NNODES + 63) / 64;  // 782
    const ushort* hin = xb;
    for (int l = 0; l < 3; ++l) {
        aggregate_kernel<<<(NNODES + 15) / 16, 256, 0, stream>>>(hin, rowp, colv, tmpb, NNODES);
        mfma_gemm_kernel<true, false, false><<<gemm_grid, 256, 0, stream>>>(
            tmpb, wf + (size_t)(2 * l) * 16384, bA[l], zbb, nullptr, nullptr,
            ssum + l * 128, ssq + l * 128, nullptr, nullptr, NNODES);
        finalize_stats_kernel<<<1, 128, 0, stream>>>(ssum + l * 128, ssq + l * 128,
                                                     gm[l], bt[l], scaleb, shiftb, NNODES);
        if (l < 2) {
            mfma_gemm_kernel<false, true, false><<<gemm_grid, 256, 0, stream>>>(
                zbb, wf + (size_t)(2 * l + 1) * 16384, bB[l], hbb, scaleb, shiftb,
                nullptr, nullptr, nullptr, nullptr, NNODES);
        } else {
            mfma_gemm_kernel<false, true, true><<<gemm_grid, 256, 0, stream>>>(
                zbb, wf + (size_t)(2 * l + 1) * 16384, bB[l], nullptr, scaleb, shiftb,
                nullptr, nullptr, gptr, (float*)d_out, NNODES);
        }
        hin = hbb;
    }
}